// Round 1
// baseline (1973.156 us; speedup 1.0000x reference)
//
#include <hip/hip_runtime.h>
#include <hip/hip_bf16.h>
#include <cstdint>
#include <cstddef>

// ---------------------------------------------------------------------------
// ViT block: x = image + attn(LN(image)); out = x + MLP(LN(x))
// B=1024 S=64 E=768 H=12 DH=64 HID=3072.  All internal GEMMs bf16 MFMA
// (16x16x32), fp32 accumulate; residual spine kept fp32.
// ---------------------------------------------------------------------------

typedef __bf16 bf16;
typedef __bf16 bf16x8 __attribute__((ext_vector_type(8)));
typedef __bf16 bf16x4 __attribute__((ext_vector_type(4)));
typedef float  f32x4  __attribute__((ext_vector_type(4)));

// async global->LDS, 16B per lane.  LDS dest must be wave-uniform base;
// HW writes base + lane*16 (guide §5 caveat).
#define LDS_ASYNC16(lds, g)                                                     \
  __builtin_amdgcn_global_load_lds(                                             \
      (const __attribute__((address_space(1))) void*)(g),                       \
      (__attribute__((address_space(3))) void*)(lds), 16, 0, 0)

#define NROWS 65536   // B*S
#define E_DIM 768
#define HID_DIM 3072
#define HEADS 12

// ---------------------------------------------------------------------------
// transpose + fp32->bf16 cast:  in [K,N] row-major -> out [N,K] row-major
// ---------------------------------------------------------------------------
__global__ __launch_bounds__(256) void transpose_cast(
    const float* __restrict__ in, bf16* __restrict__ out, int K, int N) {
  __shared__ float tile[32][33];
  int tx = threadIdx.x & 31, ty = threadIdx.x >> 5;  // 32 x 8
  int n0 = blockIdx.x * 32, k0 = blockIdx.y * 32;
#pragma unroll
  for (int i = 0; i < 4; ++i)
    tile[ty + 8 * i][tx] = in[(size_t)(k0 + ty + 8 * i) * N + n0 + tx];
  __syncthreads();
#pragma unroll
  for (int i = 0; i < 4; ++i)
    out[(size_t)(n0 + ty + 8 * i) * K + k0 + tx] = (bf16)tile[tx][ty + 8 * i];
}

// ---------------------------------------------------------------------------
// LayerNorm over E=768, one wave per row, fp32 in -> bf16 out
// ---------------------------------------------------------------------------
__global__ __launch_bounds__(256) void ln_kernel(
    const float* __restrict__ x, const float* __restrict__ gam,
    const float* __restrict__ bet, bf16* __restrict__ out) {
  int row  = blockIdx.x * 4 + (threadIdx.x >> 6);
  int lane = threadIdx.x & 63;
  const float4* xr = (const float4*)(x + (size_t)row * E_DIM);
  float4 v[3];
  float s = 0.f, ss = 0.f;
#pragma unroll
  for (int i = 0; i < 3; ++i) {
    v[i] = xr[lane + 64 * i];
    s  += v[i].x + v[i].y + v[i].z + v[i].w;
    ss += v[i].x * v[i].x + v[i].y * v[i].y + v[i].z * v[i].z + v[i].w * v[i].w;
  }
#pragma unroll
  for (int m = 1; m < 64; m <<= 1) {
    s  += __shfl_xor(s, m);
    ss += __shfl_xor(ss, m);
  }
  float mean = s * (1.f / 768.f);
  float var  = ss * (1.f / 768.f) - mean * mean;
  float rstd = rsqrtf(var + 1e-6f);
  bf16x4* o = (bf16x4*)(out + (size_t)row * E_DIM);
#pragma unroll
  for (int i = 0; i < 3; ++i) {
    float4 g4 = ((const float4*)gam)[lane + 64 * i];
    float4 b4 = ((const float4*)bet)[lane + 64 * i];
    bf16x4 r;
    r[0] = (bf16)((v[i].x - mean) * rstd * g4.x + b4.x);
    r[1] = (bf16)((v[i].y - mean) * rstd * g4.y + b4.y);
    r[2] = (bf16)((v[i].z - mean) * rstd * g4.z + b4.z);
    r[3] = (bf16)((v[i].w - mean) * rstd * g4.w + b4.w);
    o[lane + 64 * i] = r;
  }
}

// ---------------------------------------------------------------------------
// Fused QKV projection + attention per (b,h).  Block = 256 thr = 4 waves,
// wave w owns q-rows [w*16, w*16+16).  Uses the S==DH==64 reshape identity:
// x_flat[b*49152 + h*4096 + s*64 + t] = image + attn[b,h,s,t]
// ---------------------------------------------------------------------------
__global__ __launch_bounds__(256) void attn_kernel(
    const bf16* __restrict__ hn, const bf16* __restrict__ WqT,
    const bf16* __restrict__ WkT, const bf16* __restrict__ WvT,
    const float* __restrict__ bq, const float* __restrict__ bk,
    const float* __restrict__ bv, const float* __restrict__ image,
    float* __restrict__ xout) {
  // phase-1 staging (16KB) aliased with phase-2+ tiles (36KB, stride-72 pad)
  __shared__ __align__(16) char smem[36864];
  bf16* As = (bf16*)smem;             // 64x32
  bf16* Bs = (bf16*)(smem + 4096);    // 3 x 64x32 (q,k,v weight tiles)
  bf16* qs = (bf16*)smem;             // 64x72 (pad: 144B rows -> 2-way = free)
  bf16* ks = (bf16*)(smem + 9216);
  bf16* vs = (bf16*)(smem + 18432);
  bf16* pT = (bf16*)(smem + 27648);   // transposed probs [t][s]

  const int t = threadIdx.x, w = t >> 6, lane = t & 63;
  const int quad = lane >> 4, l15 = lane & 15;
  const int h = blockIdx.x % HEADS, b = blockIdx.x / HEADS;

  f32x4 aq[4] = {}, ak[4] = {}, av[4] = {};
  const bf16* Ag = hn + (size_t)(b * 64) * E_DIM;
  const bf16* Qg = WqT + (size_t)(h * 64) * E_DIM;
  const bf16* Kg = WkT + (size_t)(h * 64) * E_DIM;
  const bf16* Vg = WvT + (size_t)(h * 64) * E_DIM;
  const int sr = t >> 2, skc = (t & 3) * 8;  // staging row / k-offset

  for (int k0 = 0; k0 < E_DIM; k0 += 32) {
    __syncthreads();
    size_t go = (size_t)sr * E_DIM + k0 + skc;
    LDS_ASYNC16((char*)As + w * 1024, Ag + go);
    LDS_ASYNC16((char*)Bs + w * 1024, Qg + go);
    LDS_ASYNC16((char*)Bs + 4096 + w * 1024, Kg + go);
    LDS_ASYNC16((char*)Bs + 8192 + w * 1024, Vg + go);
    __syncthreads();
    bf16x8 af = *(const bf16x8*)&As[(w * 16 + l15) * 32 + quad * 8];
#pragma unroll
    for (int ni = 0; ni < 4; ++ni) {
      bf16x8 b0 = *(const bf16x8*)&Bs[(ni * 16 + l15) * 32 + quad * 8];
      bf16x8 b1 = *(const bf16x8*)&Bs[2048 + (ni * 16 + l15) * 32 + quad * 8];
      bf16x8 b2 = *(const bf16x8*)&Bs[4096 + (ni * 16 + l15) * 32 + quad * 8];
      aq[ni] = __builtin_amdgcn_mfma_f32_16x16x32_bf16(af, b0, aq[ni], 0, 0, 0);
      ak[ni] = __builtin_amdgcn_mfma_f32_16x16x32_bf16(af, b1, ak[ni], 0, 0, 0);
      av[ni] = __builtin_amdgcn_mfma_f32_16x16x32_bf16(af, b2, av[ni], 0, 0, 0);
    }
  }
  __syncthreads();

  // bias + (q * 1/sqrt(E)) -> LDS, C-layout: row = quad*4+r, col = l15
  const float inv_sqrt_e = 0.03608439182435161f;  // 1/sqrt(768)
#pragma unroll
  for (int ni = 0; ni < 4; ++ni) {
    int d = ni * 16 + l15;
    float bqv = bq[h * 64 + d], bkv = bk[h * 64 + d], bvv = bv[h * 64 + d];
#pragma unroll
    for (int r = 0; r < 4; ++r) {
      int s = w * 16 + quad * 4 + r;
      qs[s * 72 + d] = (bf16)((aq[ni][r] + bqv) * inv_sqrt_e);
      ks[s * 72 + d] = (bf16)(ak[ni][r] + bkv);
      vs[s * 72 + d] = (bf16)(av[ni][r] + bvv);
    }
  }
  __syncthreads();

  // scores = qs @ ks^T  (wave w: rows w*16..+16, all 64 cols)
  f32x4 sc[4] = {};
#pragma unroll
  for (int kk = 0; kk < 2; ++kk) {
    bf16x8 af = *(const bf16x8*)&qs[(w * 16 + l15) * 72 + kk * 32 + quad * 8];
#pragma unroll
    for (int ni = 0; ni < 4; ++ni) {
      bf16x8 bfr = *(const bf16x8*)&ks[(ni * 16 + l15) * 72 + kk * 32 + quad * 8];
      sc[ni] = __builtin_amdgcn_mfma_f32_16x16x32_bf16(af, bfr, sc[ni], 0, 0, 0);
    }
  }

  // softmax along t: each row lives in one 16-lane quad x 4 accum registers
#pragma unroll
  for (int r = 0; r < 4; ++r) {
    float mx = fmaxf(fmaxf(sc[0][r], sc[1][r]), fmaxf(sc[2][r], sc[3][r]));
    mx = fmaxf(mx, __shfl_xor(mx, 1));
    mx = fmaxf(mx, __shfl_xor(mx, 2));
    mx = fmaxf(mx, __shfl_xor(mx, 4));
    mx = fmaxf(mx, __shfl_xor(mx, 8));
    float e0 = __expf(sc[0][r] - mx), e1 = __expf(sc[1][r] - mx);
    float e2 = __expf(sc[2][r] - mx), e3 = __expf(sc[3][r] - mx);
    float sm = e0 + e1 + e2 + e3;
    sm += __shfl_xor(sm, 1);
    sm += __shfl_xor(sm, 2);
    sm += __shfl_xor(sm, 4);
    sm += __shfl_xor(sm, 8);
    float inv = 1.f / sm;
    sc[0][r] = e0 * inv; sc[1][r] = e1 * inv;
    sc[2][r] = e2 * inv; sc[3][r] = e3 * inv;
  }

  // store P transposed: pT[t][s] so V@P B-fragments read contiguous d
#pragma unroll
  for (int ni = 0; ni < 4; ++ni) {
    int tc = ni * 16 + l15;
#pragma unroll
    for (int r = 0; r < 4; ++r) {
      int s = w * 16 + quad * 4 + r;
      pT[tc * 72 + s] = (bf16)sc[ni][r];
    }
  }
  __syncthreads();

  // attn[s][t] = sum_d v[s][d] * P[d][t]
  f32x4 ao[4] = {};
#pragma unroll
  for (int kk = 0; kk < 2; ++kk) {
    bf16x8 af = *(const bf16x8*)&vs[(w * 16 + l15) * 72 + kk * 32 + quad * 8];
#pragma unroll
    for (int ni = 0; ni < 4; ++ni) {
      bf16x8 bfr = *(const bf16x8*)&pT[(ni * 16 + l15) * 72 + kk * 32 + quad * 8];
      ao[ni] = __builtin_amdgcn_mfma_f32_16x16x32_bf16(af, bfr, ao[ni], 0, 0, 0);
    }
  }

  // x = image + attn (flat reshape identity)
  size_t base = (size_t)b * 49152 + (size_t)h * 4096;
#pragma unroll
  for (int ni = 0; ni < 4; ++ni) {
    int tc = ni * 16 + l15;
#pragma unroll
    for (int r = 0; r < 4; ++r) {
      int s = w * 16 + quad * 4 + r;
      size_t off = base + (size_t)s * 64 + tc;
      xout[off] = image[off] + ao[ni][r];
    }
  }
}

// ---------------------------------------------------------------------------
// m97-style GEMM:  C[M,N] = A[M,K] @ B^T  (B stored [N,K] bf16).
// 128x128 block tile, 4 waves 2x2, 16 MFMA + 8 ds_read_b128 per K-step,
// staging via global_load_lds width 16.
// EPI 0: bias + exact GELU -> bf16 out.   EPI 1: bias + residual -> f32 out.
// ---------------------------------------------------------------------------
template <int EPI>
__global__ __launch_bounds__(256) void gemm_bt(
    const bf16* __restrict__ A, const bf16* __restrict__ B,
    const float* __restrict__ bias, bf16* __restrict__ outb, float* outf,
    const float* resid, int M, int N, int K) {
  __shared__ __align__(16) bf16 As[128 * 32];
  __shared__ __align__(16) bf16 Bs[128 * 32];
  const int t = threadIdx.x, w = t >> 6, lane = t & 63;
  const int quad = lane >> 4, l15 = lane & 15;
  const int wm = w >> 1, wn = w & 1;
  const int bn = blockIdx.x, bm = blockIdx.y;
  const bf16* Ag = A + (size_t)bm * 128 * K;
  const bf16* Bg = B + (size_t)bn * 128 * K;

  f32x4 acc[4][4] = {};

  for (int k0 = 0; k0 < K; k0 += 32) {
    __syncthreads();
#pragma unroll
    for (int c = 0; c < 2; ++c) {
      int slot = c * 256 + t;
      size_t go = (size_t)(slot >> 2) * K + k0 + (slot & 3) * 8;
      int lo = (c * 256 + w * 64) * 16;  // wave-uniform LDS byte base
      LDS_ASYNC16((char*)As + lo, Ag + go);
      LDS_ASYNC16((char*)Bs + lo, Bg + go);
    }
    __syncthreads();
    bf16x8 af[4], bf[4];
#pragma unroll
    for (int i = 0; i < 4; ++i) {
      af[i] = *(const bf16x8*)&As[(wm * 64 + i * 16 + l15) * 32 + quad * 8];
      bf[i] = *(const bf16x8*)&Bs[(wn * 64 + i * 16 + l15) * 32 + quad * 8];
    }
#pragma unroll
    for (int mi = 0; mi < 4; ++mi)
#pragma unroll
      for (int ni = 0; ni < 4; ++ni)
        acc[mi][ni] = __builtin_amdgcn_mfma_f32_16x16x32_bf16(
            af[mi], bf[ni], acc[mi][ni], 0, 0, 0);
  }

  const int row0 = bm * 128 + wm * 64, col0 = bn * 128 + wn * 64;
#pragma unroll
  for (int mi = 0; mi < 4; ++mi) {
#pragma unroll
    for (int ni = 0; ni < 4; ++ni) {
      int col = col0 + ni * 16 + l15;
      float bc = bias[col];
#pragma unroll
      for (int r = 0; r < 4; ++r) {
        int row = row0 + mi * 16 + quad * 4 + r;
        float v = acc[mi][ni][r] + bc;
        size_t off = (size_t)row * N + col;
        if (EPI == 0) {
          float g = 0.5f * v * (1.0f + erff(v * 0.70710678118654752f));
          outb[off] = (bf16)g;
        } else {
          outf[off] = resid[off] + v;
        }
      }
    }
  }
}

// ---------------------------------------------------------------------------
extern "C" void kernel_launch(void* const* d_in, const int* in_sizes, int n_in,
                              void* d_out, int out_size, void* d_ws,
                              size_t ws_size, hipStream_t stream) {
  const float* image = (const float*)d_in[0];
  const float* ln_g  = (const float*)d_in[1];
  const float* ln_b  = (const float*)d_in[2];
  const float* Wq    = (const float*)d_in[3];
  const float* bq    = (const float*)d_in[4];
  const float* Wk    = (const float*)d_in[5];
  const float* bk    = (const float*)d_in[6];
  const float* Wv    = (const float*)d_in[7];
  const float* bv    = (const float*)d_in[8];
  const float* W1    = (const float*)d_in[9];
  const float* b1    = (const float*)d_in[10];
  const float* W2    = (const float*)d_in[11];
  const float* b2    = (const float*)d_in[12];
  float* out = (float*)d_out;

  char* ws = (char*)d_ws;
  bf16* hn  = (bf16*)ws;  ws += (size_t)NROWS * E_DIM * 2;      // 100.7 MB
  bf16* h1  = (bf16*)ws;  ws += (size_t)NROWS * HID_DIM * 2;    // 402.7 MB
  bf16* WqT = (bf16*)ws;  ws += (size_t)E_DIM * E_DIM * 2;
  bf16* WkT = (bf16*)ws;  ws += (size_t)E_DIM * E_DIM * 2;
  bf16* WvT = (bf16*)ws;  ws += (size_t)E_DIM * E_DIM * 2;
  bf16* W1T = (bf16*)ws;  ws += (size_t)E_DIM * HID_DIM * 2;
  bf16* W2T = (bf16*)ws;  ws += (size_t)E_DIM * HID_DIM * 2;

  dim3 blk(256);
  // weights -> bf16 [N,K]
  transpose_cast<<<dim3(24, 24), blk, 0, stream>>>(Wq, WqT, 768, 768);
  transpose_cast<<<dim3(24, 24), blk, 0, stream>>>(Wk, WkT, 768, 768);
  transpose_cast<<<dim3(24, 24), blk, 0, stream>>>(Wv, WvT, 768, 768);
  transpose_cast<<<dim3(96, 24), blk, 0, stream>>>(W1, W1T, 768, 3072);
  transpose_cast<<<dim3(24, 96), blk, 0, stream>>>(W2, W2T, 3072, 768);
  // hn = LN(image)
  ln_kernel<<<NROWS / 4, blk, 0, stream>>>(image, ln_g, ln_b, hn);
  // x = image + attn -> d_out
  attn_kernel<<<1024 * HEADS, blk, 0, stream>>>(hn, WqT, WkT, WvT, bq, bk, bv,
                                                image, out);
  // hn2 = LN(x)  (reuse hn buffer)
  ln_kernel<<<NROWS / 4, blk, 0, stream>>>(out, ln_g, ln_b, hn);
  // h1 = gelu(hn2 @ W1 + b1)
  gemm_bt<0><<<dim3(HID_DIM / 128, NROWS / 128), blk, 0, stream>>>(
      hn, W1T, b1, h1, nullptr, nullptr, NROWS, HID_DIM, E_DIM);
  // out = x + (h1 @ W2 + b2)   (in-place on d_out)
  gemm_bt<1><<<dim3(E_DIM / 128, NROWS / 128), blk, 0, stream>>>(
      h1, W2T, b2, nullptr, out, out, NROWS, E_DIM, HID_DIM);
}

// Round 2
// 1967.049 us; speedup vs baseline: 1.0031x; 1.0031x over previous
//
#include <hip/hip_runtime.h>
#include <hip/hip_bf16.h>
#include <cstdint>
#include <cstddef>

// ---------------------------------------------------------------------------
// ViT block: x = image + attn(LN(image)); out = x + MLP(LN(x))
// B=1024 S=64 E=768 H=12 DH=64 HID=3072.  All GEMMs bf16 MFMA 16x16x32,
// fp32 accumulate; residual spine fp32.
// R2: LDS xor-swizzle (kill 8-way ds_read_b128 conflicts), fast tanh-GELU,
// XCD-aware block decode (A-tile locality), QKV via big GEMM + lean attn.
// ---------------------------------------------------------------------------

typedef __bf16 bf16;
typedef __bf16 bf16x8 __attribute__((ext_vector_type(8)));
typedef __bf16 bf16x4 __attribute__((ext_vector_type(4)));
typedef float  f32x4  __attribute__((ext_vector_type(4)));

#define LDS_ASYNC16(lds, g)                                                     \
  __builtin_amdgcn_global_load_lds(                                             \
      (const __attribute__((address_space(1))) void*)(g),                       \
      (__attribute__((address_space(3))) void*)(lds), 16, 0, 0)

#define NROWS 65536   // B*S
#define E_DIM 768
#define HID_DIM 3072
#define HEADS 12
#define QKV_N 2304    // 3*E

// ---------------------------------------------------------------------------
// transpose + fp32->bf16 cast:  in [K,N] row-major -> out [N,K] row-major
// ---------------------------------------------------------------------------
__global__ __launch_bounds__(256) void transpose_cast(
    const float* __restrict__ in, bf16* __restrict__ out, int K, int N) {
  __shared__ float tile[32][33];
  int tx = threadIdx.x & 31, ty = threadIdx.x >> 5;  // 32 x 8
  int n0 = blockIdx.x * 32, k0 = blockIdx.y * 32;
#pragma unroll
  for (int i = 0; i < 4; ++i)
    tile[ty + 8 * i][tx] = in[(size_t)(k0 + ty + 8 * i) * N + n0 + tx];
  __syncthreads();
#pragma unroll
  for (int i = 0; i < 4; ++i)
    out[(size_t)(n0 + ty + 8 * i) * K + k0 + tx] = (bf16)tile[tx][ty + 8 * i];
}

__global__ __launch_bounds__(256) void pack_bias(
    const float* __restrict__ bq, const float* __restrict__ bk,
    const float* __restrict__ bv, float* __restrict__ o) {
  int i = blockIdx.x * 256 + threadIdx.x;  // grid 9 -> 2304
  const float* src = i < 768 ? bq : (i < 1536 ? bk : bv);
  o[i] = src[i & 767];  // 768-aligned sections
}

// ---------------------------------------------------------------------------
// LayerNorm over E=768, one wave per row, fp32 in -> bf16 out
// ---------------------------------------------------------------------------
__global__ __launch_bounds__(256) void ln_kernel(
    const float* __restrict__ x, const float* __restrict__ gam,
    const float* __restrict__ bet, bf16* __restrict__ out) {
  int row  = blockIdx.x * 4 + (threadIdx.x >> 6);
  int lane = threadIdx.x & 63;
  const float4* xr = (const float4*)(x + (size_t)row * E_DIM);
  float4 v[3];
  float s = 0.f, ss = 0.f;
#pragma unroll
  for (int i = 0; i < 3; ++i) {
    v[i] = xr[lane + 64 * i];
    s  += v[i].x + v[i].y + v[i].z + v[i].w;
    ss += v[i].x * v[i].x + v[i].y * v[i].y + v[i].z * v[i].z + v[i].w * v[i].w;
  }
#pragma unroll
  for (int m = 1; m < 64; m <<= 1) {
    s  += __shfl_xor(s, m);
    ss += __shfl_xor(ss, m);
  }
  float mean = s * (1.f / 768.f);
  float var  = ss * (1.f / 768.f) - mean * mean;
  float rstd = rsqrtf(var + 1e-6f);
  bf16x4* o = (bf16x4*)(out + (size_t)row * E_DIM);
#pragma unroll
  for (int i = 0; i < 3; ++i) {
    float4 g4 = ((const float4*)gam)[lane + 64 * i];
    float4 b4 = ((const float4*)bet)[lane + 64 * i];
    bf16x4 r;
    r[0] = (bf16)((v[i].x - mean) * rstd * g4.x + b4.x);
    r[1] = (bf16)((v[i].y - mean) * rstd * g4.y + b4.y);
    r[2] = (bf16)((v[i].z - mean) * rstd * g4.z + b4.z);
    r[3] = (bf16)((v[i].w - mean) * rstd * g4.w + b4.w);
    o[lane + 64 * i] = r;
  }
}

// ---------------------------------------------------------------------------
// Lean attention per (b,h): q,k,v tiles from packed qkv buffer, scores MFMA,
// softmax, V@P MFMA, +image residual.  S==DH==64 reshape identity:
// x_flat[b*49152 + h*4096 + s*64 + t] = image + attn[b,h,s,t]
// ---------------------------------------------------------------------------
__global__ __launch_bounds__(256) void attn_kernel(
    const bf16* __restrict__ qkv, const float* __restrict__ image,
    float* __restrict__ xout) {
  __shared__ __align__(16) bf16 qs[64 * 72];  // pad 72: 2-way = free
  __shared__ __align__(16) bf16 ks[64 * 72];
  __shared__ __align__(16) bf16 vs[64 * 72];
  __shared__ __align__(16) bf16 pT[64 * 72];

  const int t = threadIdx.x, w = t >> 6, lane = t & 63;
  const int quad = lane >> 4, l15 = lane & 15;
  const int h = blockIdx.x % HEADS, b = blockIdx.x / HEADS;

  const bf16* base = qkv + (size_t)(b * 64) * QKV_N + h * 64;
#pragma unroll
  for (int i = 0; i < 2; ++i) {
    int slot = i * 256 + t;          // 0..511
    int row = slot >> 3, c = (slot & 7) * 8;
    size_t go = (size_t)row * QKV_N + c;
    *(bf16x8*)&qs[row * 72 + c] = *(const bf16x8*)&base[go];
    *(bf16x8*)&ks[row * 72 + c] = *(const bf16x8*)&base[go + 768];
    *(bf16x8*)&vs[row * 72 + c] = *(const bf16x8*)&base[go + 1536];
  }
  __syncthreads();

  // scores = q @ k^T; wave w owns rows w*16..+16
  f32x4 sc[4] = {};
#pragma unroll
  for (int kk = 0; kk < 2; ++kk) {
    bf16x8 af = *(const bf16x8*)&qs[(w * 16 + l15) * 72 + kk * 32 + quad * 8];
#pragma unroll
    for (int ni = 0; ni < 4; ++ni) {
      bf16x8 bfr = *(const bf16x8*)&ks[(ni * 16 + l15) * 72 + kk * 32 + quad * 8];
      sc[ni] = __builtin_amdgcn_mfma_f32_16x16x32_bf16(af, bfr, sc[ni], 0, 0, 0);
    }
  }

  // scale by 1/sqrt(E) then softmax along t (row in one quad x 4 regs)
  const float inv_sqrt_e = 0.03608439182435161f;
#pragma unroll
  for (int r = 0; r < 4; ++r) {
    float s0 = sc[0][r] * inv_sqrt_e, s1 = sc[1][r] * inv_sqrt_e;
    float s2 = sc[2][r] * inv_sqrt_e, s3 = sc[3][r] * inv_sqrt_e;
    float mx = fmaxf(fmaxf(s0, s1), fmaxf(s2, s3));
    mx = fmaxf(mx, __shfl_xor(mx, 1));
    mx = fmaxf(mx, __shfl_xor(mx, 2));
    mx = fmaxf(mx, __shfl_xor(mx, 4));
    mx = fmaxf(mx, __shfl_xor(mx, 8));
    float e0 = __expf(s0 - mx), e1 = __expf(s1 - mx);
    float e2 = __expf(s2 - mx), e3 = __expf(s3 - mx);
    float sm = e0 + e1 + e2 + e3;
    sm += __shfl_xor(sm, 1);
    sm += __shfl_xor(sm, 2);
    sm += __shfl_xor(sm, 4);
    sm += __shfl_xor(sm, 8);
    float inv = 1.f / sm;
    sc[0][r] = e0 * inv; sc[1][r] = e1 * inv;
    sc[2][r] = e2 * inv; sc[3][r] = e3 * inv;
  }

  // store P transposed: pT[t][s]
#pragma unroll
  for (int ni = 0; ni < 4; ++ni) {
    int tc = ni * 16 + l15;
#pragma unroll
    for (int r = 0; r < 4; ++r) {
      int s = w * 16 + quad * 4 + r;
      pT[tc * 72 + s] = (bf16)sc[ni][r];
    }
  }
  __syncthreads();

  // attn[s][t] = sum_d v[s][d] * P[d][t]
  f32x4 ao[4] = {};
#pragma unroll
  for (int kk = 0; kk < 2; ++kk) {
    bf16x8 af = *(const bf16x8*)&vs[(w * 16 + l15) * 72 + kk * 32 + quad * 8];
#pragma unroll
    for (int ni = 0; ni < 4; ++ni) {
      bf16x8 bfr = *(const bf16x8*)&pT[(ni * 16 + l15) * 72 + kk * 32 + quad * 8];
      ao[ni] = __builtin_amdgcn_mfma_f32_16x16x32_bf16(af, bfr, ao[ni], 0, 0, 0);
    }
  }

  size_t base_o = (size_t)b * 49152 + (size_t)h * 4096;
#pragma unroll
  for (int ni = 0; ni < 4; ++ni) {
    int tc = ni * 16 + l15;
#pragma unroll
    for (int r = 0; r < 4; ++r) {
      int s = w * 16 + quad * 4 + r;
      size_t off = base_o + (size_t)s * 64 + tc;
      xout[off] = image[off] + ao[ni][r];
    }
  }
}

// ---------------------------------------------------------------------------
// fast GELU: tanh form, robust at +-inf (no inf/inf)
// ---------------------------------------------------------------------------
__device__ inline float gelu_f(float x) {
  float u = x * (0.7978845608028654f + 0.0356774081f * x * x);
  float e = __expf(2.f * u);
  float th = 1.f - 2.f / (e + 1.f);
  return 0.5f * x * (1.f + th);
}

// ---------------------------------------------------------------------------
// m97-style GEMM:  C[M,N] = A[M,K] @ B^T  (B stored [N,K] bf16).
// 128x128 tile, 4 waves 2x2.  LDS chunk xor-swizzle: chunk c of row r stored
// at slot c ^ ((r>>1)&3) -> ds_read_b128 2-way banked (free) vs 8-way.
// XCD decode: all N-tiles of an M-row share flat%8 -> same XCD L2.
// EPI 0: bias+GELU->bf16.  1: bias+resid->f32.  2: bias->bf16.
// ---------------------------------------------------------------------------
template <int EPI>
__global__ __launch_bounds__(256) void gemm_bt(
    const bf16* __restrict__ A, const bf16* __restrict__ B,
    const float* __restrict__ bias, bf16* __restrict__ outb, float* outf,
    const float* resid, int M, int N, int K) {
  __shared__ __align__(16) bf16 As[128 * 32];
  __shared__ __align__(16) bf16 Bs[128 * 32];
  const int t = threadIdx.x, w = t >> 6, lane = t & 63;
  const int quad = lane >> 4, l15 = lane & 15;
  const int wm = w >> 1, wn = w & 1;

  // XCD-aware decode (M-tiles % 8 == 0 required)
  const int Nt = gridDim.x;
  int flat = blockIdx.x + Nt * blockIdx.y;
  int xcd = flat & 7, rest = flat >> 3;
  int bn = rest % Nt, bm = (rest / Nt) * 8 + xcd;

  const bf16* Ag = A + (size_t)bm * 128 * K;
  const bf16* Bg = B + (size_t)bn * 128 * K;

  f32x4 acc[4][4] = {};
  const int swz = (l15 >> 1) & 3;  // fragment-read chunk swizzle

  for (int k0 = 0; k0 < K; k0 += 32) {
    __syncthreads();
#pragma unroll
    for (int c = 0; c < 2; ++c) {
      int slot = c * 256 + t;
      int row = slot >> 2;
      int cg = (slot & 3) ^ ((row >> 1) & 3);
      size_t go = (size_t)row * K + k0 + cg * 8;
      int lo = (c * 256 + w * 64) * 16;  // wave-uniform LDS byte base
      LDS_ASYNC16((char*)As + lo, Ag + go);
      LDS_ASYNC16((char*)Bs + lo, Bg + go);
    }
    __syncthreads();
    bf16x8 af[4], bfr[4];
#pragma unroll
    for (int i = 0; i < 4; ++i) {
      af[i]  = *(const bf16x8*)&As[(wm * 64 + i * 16 + l15) * 32 + (quad ^ swz) * 8];
      bfr[i] = *(const bf16x8*)&Bs[(wn * 64 + i * 16 + l15) * 32 + (quad ^ swz) * 8];
    }
#pragma unroll
    for (int mi = 0; mi < 4; ++mi)
#pragma unroll
      for (int ni = 0; ni < 4; ++ni)
        acc[mi][ni] = __builtin_amdgcn_mfma_f32_16x16x32_bf16(
            af[mi], bfr[ni], acc[mi][ni], 0, 0, 0);
  }

  const int row0 = bm * 128 + wm * 64, col0 = bn * 128 + wn * 64;
#pragma unroll
  for (int mi = 0; mi < 4; ++mi) {
#pragma unroll
    for (int ni = 0; ni < 4; ++ni) {
      int col = col0 + ni * 16 + l15;
      float bc = bias[col];
#pragma unroll
      for (int r = 0; r < 4; ++r) {
        int row = row0 + mi * 16 + quad * 4 + r;
        float v = acc[mi][ni][r] + bc;
        size_t off = (size_t)row * N + col;
        if (EPI == 0) {
          outb[off] = (bf16)gelu_f(v);
        } else if (EPI == 1) {
          outf[off] = resid[off] + v;
        } else {
          outb[off] = (bf16)v;
        }
      }
    }
  }
}

// ---------------------------------------------------------------------------
extern "C" void kernel_launch(void* const* d_in, const int* in_sizes, int n_in,
                              void* d_out, int out_size, void* d_ws,
                              size_t ws_size, hipStream_t stream) {
  const float* image = (const float*)d_in[0];
  const float* ln_g  = (const float*)d_in[1];
  const float* ln_b  = (const float*)d_in[2];
  const float* Wq    = (const float*)d_in[3];
  const float* bq    = (const float*)d_in[4];
  const float* Wk    = (const float*)d_in[5];
  const float* bk    = (const float*)d_in[6];
  const float* Wv    = (const float*)d_in[7];
  const float* bv    = (const float*)d_in[8];
  const float* W1    = (const float*)d_in[9];
  const float* b1    = (const float*)d_in[10];
  const float* W2    = (const float*)d_in[11];
  const float* b2    = (const float*)d_in[12];
  float* out = (float*)d_out;

  char* ws = (char*)d_ws;
  bf16* hn   = (bf16*)ws;  ws += (size_t)NROWS * E_DIM * 2;      // 100.7 MB
  // h1 (65536x3072 bf16, 402 MB) and qkv (65536x2304 bf16, 302 MB) have
  // disjoint live ranges -> alias the same region.
  bf16* h1   = (bf16*)ws;
  bf16* qkv  = (bf16*)ws;  ws += (size_t)NROWS * HID_DIM * 2;
  bf16* WqkvT = (bf16*)ws; ws += (size_t)QKV_N * E_DIM * 2;      // packed [2304,768]
  bf16* W1T  = (bf16*)ws;  ws += (size_t)E_DIM * HID_DIM * 2;
  bf16* W2T  = (bf16*)ws;  ws += (size_t)E_DIM * HID_DIM * 2;
  float* bqkv = (float*)ws; ws += QKV_N * 4;

  dim3 blk(256);
  // weights -> bf16 [N,K]; Wq|Wk|Wv packed into one [2304,768]
  transpose_cast<<<dim3(24, 24), blk, 0, stream>>>(Wq, WqkvT, 768, 768);
  transpose_cast<<<dim3(24, 24), blk, 0, stream>>>(Wk, WqkvT + 768 * 768, 768, 768);
  transpose_cast<<<dim3(24, 24), blk, 0, stream>>>(Wv, WqkvT + 2 * 768 * 768, 768, 768);
  transpose_cast<<<dim3(96, 24), blk, 0, stream>>>(W1, W1T, 768, 3072);
  transpose_cast<<<dim3(24, 96), blk, 0, stream>>>(W2, W2T, 3072, 768);
  pack_bias<<<dim3(9), blk, 0, stream>>>(bq, bk, bv, bqkv);

  // hn = LN(image)
  ln_kernel<<<NROWS / 4, blk, 0, stream>>>(image, ln_g, ln_b, hn);
  // qkv = hn @ Wqkv^T + bqkv   [65536, 2304] bf16
  gemm_bt<2><<<dim3(QKV_N / 128, NROWS / 128), blk, 0, stream>>>(
      hn, WqkvT, bqkv, qkv, nullptr, nullptr, NROWS, QKV_N, E_DIM);
  // x = image + attn -> d_out
  attn_kernel<<<1024 * HEADS, blk, 0, stream>>>(qkv, image, out);
  // hn2 = LN(x)  (reuse hn)
  ln_kernel<<<NROWS / 4, blk, 0, stream>>>(out, ln_g, ln_b, hn);
  // h1 = gelu(hn2 @ W1 + b1)
  gemm_bt<0><<<dim3(HID_DIM / 128, NROWS / 128), blk, 0, stream>>>(
      hn, W1T, b1, h1, nullptr, nullptr, NROWS, HID_DIM, E_DIM);
  // out = x + (h1 @ W2 + b2)
  gemm_bt<1><<<dim3(E_DIM / 128, NROWS / 128), blk, 0, stream>>>(
      h1, W2T, b2, nullptr, out, out, NROWS, E_DIM, HID_DIM);
}